// Round 15
// baseline (240.983 us; speedup 1.0000x reference)
//
#include <hip/hip_runtime.h>
#include <stdint.h>
#include <stddef.h>

#define DIM 768
#define NH  12
#define NKV 4
#define HD  64
#define TT  128
#define NS  256

typedef __attribute__((ext_vector_type(8))) short bf16x8;
typedef __attribute__((ext_vector_type(4))) float f32x4;
typedef __attribute__((ext_vector_type(4))) unsigned int u32x4;
typedef __attribute__((ext_vector_type(2))) unsigned int u32x2;

__device__ __forceinline__ unsigned short f2bf(float f) {
  union { float f; unsigned int u; } v; v.f = f;
  return (unsigned short)((v.u + 0x7FFFu + ((v.u >> 16) & 1u)) >> 16);
}

__device__ __forceinline__ void gload_lds16(const void* g, void* l) {
  __builtin_amdgcn_global_load_lds(
      (const __attribute__((address_space(1))) unsigned int*)g,
      (__attribute__((address_space(3))) unsigned int*)l, 16, 0, 0);
}

// ---------------- kernel 0: prep (weights + x->bf16 relayout) ----------------
__global__ __launch_bounds__(256)
void prep_kernel(const float* __restrict__ x, const float* __restrict__ Wq,
                 const float* __restrict__ Wk, const float* __restrict__ Wv,
                 const float* __restrict__ Wo, unsigned short* __restrict__ Wt,
                 unsigned short* __restrict__ WoT, unsigned short* __restrict__ xb) {
  const int b = blockIdx.x, tid = threadIdx.x;
  if (b < 6144) {
    int idx = b * 256 + tid;
    const int n1 = 1280 * DIM;
    if (idx < n1) {
      int c = idx / DIM, kk = idx - c * DIM;
      float v;
      if (c < 768)       v = Wq[kk * 768 + c];
      else if (c < 1024) v = Wk[kk * 256 + (c - 768)];
      else               v = Wv[kk * 256 + (c - 1024)];
      Wt[idx] = f2bf(v);
    } else {
      int i2 = idx - n1;
      int c = i2 / DIM, kk = i2 - c * DIM;
      WoT[i2] = f2bf(Wo[kk * 768 + c]);
    }
  } else {
    int g = (b - 6144) * 256 + tid;
    int r = g / 192;                  // r = t*NS + n
    int k = g - r * 192;
    int t = r >> 8, n = r & 255;
    f32x4 f = *reinterpret_cast<const f32x4*>(x + (size_t)g * 4);
    u32x2 pk;
    pk[0] = (unsigned)f2bf(f[0]) | ((unsigned)f2bf(f[1]) << 16);
    pk[1] = (unsigned)f2bf(f[2]) | ((unsigned)f2bf(f[3]) << 16);
    *reinterpret_cast<u32x2*>(xb + (size_t)((n << 7) + t) * DIM + k * 4) = pk;
  }
}

// ---------------- kernel 1: QKV projection + QKNorm (R4/R12 structure) ----------------
__global__ __launch_bounds__(512, 2)
void qkv_kernel(const unsigned short* __restrict__ xb, const float* __restrict__ qnw,
                const float* __restrict__ knw, const unsigned short* __restrict__ Wt,
                unsigned short* __restrict__ qb, unsigned short* __restrict__ kb,
                unsigned short* __restrict__ vTb) {
  extern __shared__ unsigned short lds[];
  const int b = blockIdx.x;
  const int x8 = b & 7, idx = b >> 3;
  const int cbt = idx % 5;                 // col-tile: 0-2 q, 3 k, 4 v
  const int n   = (idx / 5) * 8 + x8;
  const int tid = threadIdx.x;
  const int wave = tid >> 6, lane = tid & 63;
  const int cl = lane & 15, rowg = lane >> 4;
  const int wmw = wave >> 2, wn = wave & 3;
  const int l8 = lane >> 3, s8 = lane & 7;
  const unsigned short* asrc = xb + (size_t)(n * TT + l8) * DIM + (s8 ^ l8) * 8;
  const unsigned short* bsrc = Wt + (size_t)(cbt * 256 + l8) * DIM + (s8 ^ l8) * 8;
  const int swzr = (cl & 7) << 4;
  f32x4 acc[4][4] = {};

#define QKV_STAGE(buf, ko)                                                  \
  {                                                                         \
    unsigned short* Ad = lds + (buf) * 24576;                               \
    unsigned short* Bd = Ad + 8192;                                         \
    _Pragma("unroll")                                                       \
    for (int i = 0; i < 2; ++i) {                                           \
      const int rr = i * 64 + wave * 8;                                     \
      gload_lds16(asrc + (size_t)rr * DIM + (ko), Ad + rr * 64);            \
    }                                                                       \
    _Pragma("unroll")                                                       \
    for (int i = 0; i < 4; ++i) {                                           \
      const int rr = i * 64 + wave * 8;                                     \
      gload_lds16(bsrc + (size_t)rr * DIM + (ko), Bd + rr * 64);            \
    }                                                                       \
  }

  QKV_STAGE(0, 0);
  __syncthreads();
  for (int kt = 0; kt < 12; ++kt) {
    if (kt < 11) QKV_STAGE((kt + 1) & 1, (kt + 1) * 64);
    const char* Ab = (const char*)(lds + (kt & 1) * 24576);
    const char* Bb = Ab + 16384;
    #pragma unroll
    for (int ks = 0; ks < 2; ++ks) {
      bf16x8 a[4], bb[4];
      #pragma unroll
      for (int m = 0; m < 4; ++m)
        a[m] = *(const bf16x8*)(Ab + (wmw * 64 + m * 16 + cl) * 128 + ((ks * 64 + rowg * 16) ^ swzr));
      #pragma unroll
      for (int nn = 0; nn < 4; ++nn)
        bb[nn] = *(const bf16x8*)(Bb + (wn * 64 + nn * 16 + cl) * 128 + ((ks * 64 + rowg * 16) ^ swzr));
      #pragma unroll
      for (int m = 0; m < 4; ++m)
        #pragma unroll
        for (int nn = 0; nn < 4; ++nn)
          acc[m][nn] = __builtin_amdgcn_mfma_f32_16x16x32_bf16(a[m], bb[nn], acc[m][nn], 0, 0, 0);
    }
    __syncthreads();
  }
#undef QKV_STAGE

  if (cbt == 4) {
    const int kv = wn;
    unsigned short* dst = vTb + (size_t)((n * NKV + kv) * HD) * TT;
    #pragma unroll
    for (int m = 0; m < 4; ++m) {
      const int tb = wmw * 64 + m * 16 + rowg * 4;
      #pragma unroll
      for (int nn = 0; nn < 4; ++nn) {
        const int d = nn * 16 + cl;
        u32x2 pk;
        pk[0] = (unsigned)f2bf(acc[m][nn][0]) | ((unsigned)f2bf(acc[m][nn][1]) << 16);
        pk[1] = (unsigned)f2bf(acc[m][nn][2]) | ((unsigned)f2bf(acc[m][nn][3]) << 16);
        *reinterpret_cast<u32x2*>(dst + (size_t)d * TT + tb) = pk;
      }
    }
  } else {
    const int isq = (cbt < 3);
    const float* nw = isq ? qnw : knw;
    float wfrag[4];
    #pragma unroll
    for (int nn = 0; nn < 4; ++nn) wfrag[nn] = nw[nn * 16 + cl];
    const float rs = isq ? 0.125f : 1.0f;  // fold attention SCALE into q
    unsigned short* dst;
    if (isq) { const int hh = cbt * 4 + wn; dst = qb + (size_t)(n * NH + hh) * TT * HD; }
    else     { const int kv = wn;           dst = kb + (size_t)(n * NKV + kv) * TT * HD; }
    #pragma unroll
    for (int m = 0; m < 4; ++m) {
      #pragma unroll
      for (int j = 0; j < 4; ++j) {
        const int t = wmw * 64 + m * 16 + rowg * 4 + j;
        float ss = 0.f;
        #pragma unroll
        for (int nn = 0; nn < 4; ++nn) { float v = acc[m][nn][j]; ss += v * v; }
        #pragma unroll
        for (int dlt = 1; dlt < 16; dlt <<= 1) ss += __shfl_xor(ss, dlt);
        const float r = rsqrtf(ss * (1.f / 64.f) + 1e-6f) * rs;
        #pragma unroll
        for (int nn = 0; nn < 4; ++nn)
          dst[(size_t)t * HD + nn * 16 + cl] = f2bf(acc[m][nn][j] * r * wfrag[nn]);
      }
    }
  }
}

// ---------------- kernel 2: attention, staging-free, barrier-free ----------------
// K/V/Q fragments read DIRECTLY from global (qb/kb/vTb are L2/L3-resident and
// already in fragment-friendly layouts; the LDS copies were pure overhead).
// LDS = Pl only (34.8KB) -> 4 blocks/CU, whole grid co-resident, 0 barriers.
// Pl rows are wave-private (write band == read band), same-wave lgkmcnt dep.
__global__ __launch_bounds__(256)
void attn_kernel(const unsigned short* __restrict__ qb, const unsigned short* __restrict__ kb,
                 const unsigned short* __restrict__ vTb, unsigned short* __restrict__ ab) {
  extern __shared__ char smem[];
  unsigned short (*Pl)[136] = reinterpret_cast<unsigned short (*)[136]>(smem);  // 34816 B
  const int b = blockIdx.x;
  const int x8 = b & 7, idx = b >> 3;
  const int kv = idx & 3;
  const int n  = (idx >> 2) * 8 + x8;
  const int tid = threadIdx.x, wave = tid >> 6, lane = tid & 63;
  const int cl = lane & 15, rowg = lane >> 4;

  const unsigned short* ksrc = kb  + (size_t)(n * NKV + kv) * TT * HD;
  const unsigned short* vsrc = vTb + (size_t)(n * NKV + kv) * HD * TT;

  for (int hh = 0; hh < 3; ++hh) {
    const int h = kv * 3 + hh;
    const unsigned short* qsrc = qb + (size_t)(n * NH + h) * TT * HD;
    f32x4 sc[2][8] = {};
    #pragma unroll
    for (int ks = 0; ks < 2; ++ks) {
      bf16x8 a[2], bbf[8];
      #pragma unroll
      for (int m = 0; m < 2; ++m)
        a[m] = *reinterpret_cast<const bf16x8*>(
            qsrc + (size_t)(wave * 32 + m * 16 + cl) * HD + ks * 32 + rowg * 8);
      #pragma unroll
      for (int nn = 0; nn < 8; ++nn)   // K-frag direct from global (L2-hot)
        bbf[nn] = *reinterpret_cast<const bf16x8*>(
            ksrc + (size_t)(nn * 16 + cl) * HD + ks * 32 + rowg * 8);
      #pragma unroll
      for (int m = 0; m < 2; ++m)
        #pragma unroll
        for (int nn = 0; nn < 8; ++nn)
          sc[m][nn] = __builtin_amdgcn_mfma_f32_16x16x32_bf16(a[m], bbf[nn], sc[m][nn], 0, 0, 0);
    }
    // soft cap (Pade) + causal + no-max softmax; rows live in 16-lane groups
    #pragma unroll
    for (int m = 0; m < 2; ++m) {
      #pragma unroll
      for (int j = 0; j < 4; ++j) {
        const int rowv = wave * 32 + m * 16 + rowg * 4 + j;
        float e8[8];
        float sum = 0.f;
        #pragma unroll
        for (int nn = 0; nn < 8; ++nn) {
          float s = sc[m][nn][j];
          const float z2 = s * s * 4.0e-4f;
          s = s * (27.f + z2) * __builtin_amdgcn_rcpf(27.f + 9.f * z2);
          float e = __expf(s - 50.f);
          if (nn * 16 + cl > rowv) e = 0.f;
          e8[nn] = e;
          sum += e;
        }
        #pragma unroll
        for (int d = 1; d < 16; d <<= 1) sum += __shfl_xor(sum, d);
        const float inv = __builtin_amdgcn_rcpf(sum);
        #pragma unroll
        for (int nn = 0; nn < 8; ++nn)
          Pl[rowv][nn * 16 + cl] = f2bf(e8[nn] * inv);
      }
    }
    // PV: Pl same-wave dep (lgkmcnt, no barrier); V^T frags direct from global
    f32x4 o[2][4] = {};
    #pragma unroll
    for (int ks = 0; ks < 4; ++ks) {
      bf16x8 a[2], bbf[4];
      #pragma unroll
      for (int m = 0; m < 2; ++m)
        a[m] = *reinterpret_cast<const bf16x8*>(&Pl[wave * 32 + m * 16 + cl][ks * 32 + rowg * 8]);
      #pragma unroll
      for (int nn = 0; nn < 4; ++nn)
        bbf[nn] = *reinterpret_cast<const bf16x8*>(
            vsrc + (size_t)(nn * 16 + cl) * TT + ks * 32 + rowg * 8);
      #pragma unroll
      for (int m = 0; m < 2; ++m)
        #pragma unroll
        for (int nn = 0; nn < 4; ++nn)
          o[m][nn] = __builtin_amdgcn_mfma_f32_16x16x32_bf16(a[m], bbf[nn], o[m][nn], 0, 0, 0);
    }
    unsigned short* dst = ab + (size_t)n * TT * DIM + h * HD;
    #pragma unroll
    for (int m = 0; m < 2; ++m)
      #pragma unroll
      for (int j = 0; j < 4; ++j) {
        int t = wave * 32 + m * 16 + rowg * 4 + j;
        #pragma unroll
        for (int nn = 0; nn < 4; ++nn)
          dst[(size_t)t * DIM + nn * 16 + cl] = f2bf(o[m][nn][j]);
      }
    // no barrier: next head rewrites only this wave's Pl rows
  }
}

// ---------------- kernel 3: output projection (R12 structure) ----------------
__global__ __launch_bounds__(512, 2)
void out_kernel(const unsigned short* __restrict__ ab, const unsigned short* __restrict__ WoT,
                float* __restrict__ out) {
  extern __shared__ unsigned short lds[];
  const int b = blockIdx.x;
  const int x8 = b & 7, idx = b >> 3;
  const int cbt = idx % 3;
  const int n   = (idx / 3) * 8 + x8;
  const int tid = threadIdx.x;
  const int wave = tid >> 6, lane = tid & 63;
  const int cl = lane & 15, rowg = lane >> 4;
  const int wmw = wave >> 2, wn = wave & 3;
  const int l8 = lane >> 3, s8 = lane & 7;
  const unsigned short* asrc = ab  + (size_t)(n * TT + l8) * DIM + (s8 ^ l8) * 8;
  const unsigned short* bsrc = WoT + (size_t)(cbt * 256 + l8) * DIM + (s8 ^ l8) * 8;
  const int swzr = (cl & 7) << 4;
  f32x4 acc[4][4] = {};

#define OUT_STAGE(buf, ko)                                                  \
  {                                                                         \
    unsigned short* Ad = lds + (buf) * 24576;                               \
    unsigned short* Bd = Ad + 8192;                                         \
    _Pragma("unroll")                                                       \
    for (int i = 0; i < 2; ++i) {                                           \
      const int rr = i * 64 + wave * 8;                                     \
      gload_lds16(asrc + (size_t)rr * DIM + (ko), Ad + rr * 64);            \
    }                                                                       \
    _Pragma("unroll")                                                       \
    for (int i = 0; i < 4; ++i) {                                           \
      const int rr = i * 64 + wave * 8;                                     \
      gload_lds16(bsrc + (size_t)rr * DIM + (ko), Bd + rr * 64);            \
    }                                                                       \
  }

  OUT_STAGE(0, 0);
  __syncthreads();
  for (int kt = 0; kt < 12; ++kt) {
    if (kt < 11) OUT_STAGE((kt + 1) & 1, (kt + 1) * 64);
    const char* Ab = (const char*)(lds + (kt & 1) * 24576);
    const char* Bb = Ab + 16384;
    #pragma unroll
    for (int ks = 0; ks < 2; ++ks) {
      bf16x8 a[4], bb[4];
      #pragma unroll
      for (int m = 0; m < 4; ++m)
        a[m] = *(const bf16x8*)(Ab + (wmw * 64 + m * 16 + cl) * 128 + ((ks * 64 + rowg * 16) ^ swzr));
      #pragma unroll
      for (int nn = 0; nn < 4; ++nn)
        bb[nn] = *(const bf16x8*)(Bb + (wn * 64 + nn * 16 + cl) * 128 + ((ks * 64 + rowg * 16) ^ swzr));
      #pragma unroll
      for (int m = 0; m < 4; ++m)
        #pragma unroll
        for (int nn = 0; nn < 4; ++nn)
          acc[m][nn] = __builtin_amdgcn_mfma_f32_16x16x32_bf16(a[m], bb[nn], acc[m][nn], 0, 0, 0);
    }
    __syncthreads();
  }
#undef OUT_STAGE
  #pragma unroll
  for (int m = 0; m < 4; ++m)
    #pragma unroll
    for (int j = 0; j < 4; ++j) {
      int t = wmw * 64 + m * 16 + rowg * 4 + j;
      #pragma unroll
      for (int nn = 0; nn < 4; ++nn)
        out[(size_t)(t * NS + n) * DIM + cbt * 256 + wn * 64 + nn * 16 + cl] = acc[m][nn][j];
    }
}

// ---------------- launch ----------------
extern "C" void kernel_launch(void* const* d_in, const int* in_sizes, int n_in,
                              void* d_out, int out_size, void* d_ws, size_t ws_size,
                              hipStream_t stream) {
  const float* x   = (const float*)d_in[0];
  const float* Wq  = (const float*)d_in[1];
  const float* Wk  = (const float*)d_in[2];
  const float* Wv  = (const float*)d_in[3];
  const float* Wo  = (const float*)d_in[4];
  const float* qnw = (const float*)d_in[5];
  const float* knw = (const float*)d_in[6];
  (void)in_sizes; (void)n_in; (void)out_size;

  char* ws = (char*)d_ws;
  unsigned short* Wt  = (unsigned short*)(ws + 0);          // 1,966,080
  unsigned short* WoT = (unsigned short*)(ws + 1966080);    // 1,179,648
  unsigned short* qb  = (unsigned short*)(ws + 3145728);    // 50,331,648
  unsigned short* kb  = (unsigned short*)(ws + 53477376);   // 16,777,216
  unsigned short* vTb = (unsigned short*)(ws + 70254592);   // 16,777,216
  unsigned short* ab  = (unsigned short*)(ws + 87031808);   // 50,331,648
  unsigned short* xb  = ab;                                 // alias (qkv reads xb before attn writes ab)
  if (ws_size < 137363456) return;

  hipFuncSetAttribute(reinterpret_cast<const void*>(qkv_kernel),
                      hipFuncAttributeMaxDynamicSharedMemorySize, 98304);
  hipFuncSetAttribute(reinterpret_cast<const void*>(out_kernel),
                      hipFuncAttributeMaxDynamicSharedMemorySize, 98304);
  hipFuncSetAttribute(reinterpret_cast<const void*>(attn_kernel),
                      hipFuncAttributeMaxDynamicSharedMemorySize, 34816);

  prep_kernel<<<30720, 256, 0, stream>>>(x, Wq, Wk, Wv, Wo, Wt, WoT, xb);
  qkv_kernel<<<1280, 512, 98304, stream>>>(xb, qnw, knw, Wt, qb, kb, vTb);
  attn_kernel<<<1024, 256, 34816, stream>>>(qb, kb, vTb, ab);
  out_kernel<<<768, 512, 98304, stream>>>(ab, WoT, (float*)d_out);
}

// Round 16
// 211.378 us; speedup vs baseline: 1.1401x; 1.1401x over previous
//
#include <hip/hip_runtime.h>
#include <stdint.h>
#include <stddef.h>

#define DIM 768
#define NH  12
#define NKV 4
#define HD  64
#define TT  128
#define NS  256

typedef __attribute__((ext_vector_type(8))) short bf16x8;
typedef __attribute__((ext_vector_type(4))) float f32x4;
typedef __attribute__((ext_vector_type(4))) unsigned int u32x4;
typedef __attribute__((ext_vector_type(2))) unsigned int u32x2;

__device__ __forceinline__ unsigned short f2bf(float f) {
  union { float f; unsigned int u; } v; v.f = f;
  return (unsigned short)((v.u + 0x7FFFu + ((v.u >> 16) & 1u)) >> 16);
}

__device__ __forceinline__ void gload_lds16(const void* g, void* l) {
  __builtin_amdgcn_global_load_lds(
      (const __attribute__((address_space(1))) unsigned int*)g,
      (__attribute__((address_space(3))) unsigned int*)l, 16, 0, 0);
}

// ---------------- kernel 0: prep (weights + x->bf16 relayout) ----------------
__global__ __launch_bounds__(256)
void prep_kernel(const float* __restrict__ x, const float* __restrict__ Wq,
                 const float* __restrict__ Wk, const float* __restrict__ Wv,
                 const float* __restrict__ Wo, unsigned short* __restrict__ Wt,
                 unsigned short* __restrict__ WoT, unsigned short* __restrict__ xb) {
  const int b = blockIdx.x, tid = threadIdx.x;
  if (b < 6144) {
    int idx = b * 256 + tid;
    const int n1 = 1280 * DIM;
    if (idx < n1) {
      int c = idx / DIM, kk = idx - c * DIM;
      float v;
      if (c < 768)       v = Wq[kk * 768 + c];
      else if (c < 1024) v = Wk[kk * 256 + (c - 768)];
      else               v = Wv[kk * 256 + (c - 1024)];
      Wt[idx] = f2bf(v);
    } else {
      int i2 = idx - n1;
      int c = i2 / DIM, kk = i2 - c * DIM;
      WoT[i2] = f2bf(Wo[kk * 768 + c]);
    }
  } else {
    int g = (b - 6144) * 256 + tid;
    int r = g / 192;                  // r = t*NS + n
    int k = g - r * 192;
    int t = r >> 8, n = r & 255;
    f32x4 f = *reinterpret_cast<const f32x4*>(x + (size_t)g * 4);
    u32x2 pk;
    pk[0] = (unsigned)f2bf(f[0]) | ((unsigned)f2bf(f[1]) << 16);
    pk[1] = (unsigned)f2bf(f[2]) | ((unsigned)f2bf(f[3]) << 16);
    *reinterpret_cast<u32x2*>(xb + (size_t)((n << 7) + t) * DIM + k * 4) = pk;
  }
}

// ---------------- kernel 1: QKV projection + QKNorm (R4 structure) ----------------
__global__ __launch_bounds__(512, 2)
void qkv_kernel(const unsigned short* __restrict__ xb, const float* __restrict__ qnw,
                const float* __restrict__ knw, const unsigned short* __restrict__ Wt,
                unsigned short* __restrict__ qb, unsigned short* __restrict__ kb,
                unsigned short* __restrict__ vTb) {
  extern __shared__ unsigned short lds[];
  const int b = blockIdx.x;
  const int x8 = b & 7, idx = b >> 3;
  const int cbt = idx % 5;                 // col-tile: 0-2 q, 3 k, 4 v
  const int n   = (idx / 5) * 8 + x8;
  const int tid = threadIdx.x;
  const int wave = tid >> 6, lane = tid & 63;
  const int cl = lane & 15, rowg = lane >> 4;
  const int wmw = wave >> 2, wn = wave & 3;
  const int l8 = lane >> 3, s8 = lane & 7;
  const unsigned short* asrc = xb + (size_t)(n * TT + l8) * DIM + (s8 ^ l8) * 8;
  const unsigned short* bsrc = Wt + (size_t)(cbt * 256 + l8) * DIM + (s8 ^ l8) * 8;
  const int swzr = (cl & 7) << 4;
  f32x4 acc[4][4] = {};

#define QKV_STAGE(buf, ko)                                                  \
  {                                                                         \
    unsigned short* Ad = lds + (buf) * 24576;                               \
    unsigned short* Bd = Ad + 8192;                                         \
    _Pragma("unroll")                                                       \
    for (int i = 0; i < 2; ++i) {                                           \
      const int rr = i * 64 + wave * 8;                                     \
      gload_lds16(asrc + (size_t)rr * DIM + (ko), Ad + rr * 64);            \
    }                                                                       \
    _Pragma("unroll")                                                       \
    for (int i = 0; i < 4; ++i) {                                           \
      const int rr = i * 64 + wave * 8;                                     \
      gload_lds16(bsrc + (size_t)rr * DIM + (ko), Bd + rr * 64);            \
    }                                                                       \
  }

  QKV_STAGE(0, 0);
  __syncthreads();
  for (int kt = 0; kt < 12; ++kt) {
    if (kt < 11) QKV_STAGE((kt + 1) & 1, (kt + 1) * 64);
    const char* Ab = (const char*)(lds + (kt & 1) * 24576);
    const char* Bb = Ab + 16384;
    #pragma unroll
    for (int ks = 0; ks < 2; ++ks) {
      bf16x8 a[4], bb[4];
      #pragma unroll
      for (int m = 0; m < 4; ++m)
        a[m] = *(const bf16x8*)(Ab + (wmw * 64 + m * 16 + cl) * 128 + ((ks * 64 + rowg * 16) ^ swzr));
      #pragma unroll
      for (int nn = 0; nn < 4; ++nn)
        bb[nn] = *(const bf16x8*)(Bb + (wn * 64 + nn * 16 + cl) * 128 + ((ks * 64 + rowg * 16) ^ swzr));
      #pragma unroll
      for (int m = 0; m < 4; ++m)
        #pragma unroll
        for (int nn = 0; nn < 4; ++nn)
          acc[m][nn] = __builtin_amdgcn_mfma_f32_16x16x32_bf16(a[m], bb[nn], acc[m][nn], 0, 0, 0);
    }
    __syncthreads();
  }
#undef QKV_STAGE

  if (cbt == 4) {
    const int kv = wn;
    unsigned short* dst = vTb + (size_t)((n * NKV + kv) * HD) * TT;
    #pragma unroll
    for (int m = 0; m < 4; ++m) {
      const int tb = wmw * 64 + m * 16 + rowg * 4;
      #pragma unroll
      for (int nn = 0; nn < 4; ++nn) {
        const int d = nn * 16 + cl;
        u32x2 pk;
        pk[0] = (unsigned)f2bf(acc[m][nn][0]) | ((unsigned)f2bf(acc[m][nn][1]) << 16);
        pk[1] = (unsigned)f2bf(acc[m][nn][2]) | ((unsigned)f2bf(acc[m][nn][3]) << 16);
        *reinterpret_cast<u32x2*>(dst + (size_t)d * TT + tb) = pk;
      }
    }
  } else {
    const int isq = (cbt < 3);
    const float* nw = isq ? qnw : knw;
    float wfrag[4];
    #pragma unroll
    for (int nn = 0; nn < 4; ++nn) wfrag[nn] = nw[nn * 16 + cl];
    const float rs = isq ? 0.125f : 1.0f;  // fold attention SCALE into q
    unsigned short* dst;
    if (isq) { const int hh = cbt * 4 + wn; dst = qb + (size_t)(n * NH + hh) * TT * HD; }
    else     { const int kv = wn;           dst = kb + (size_t)(n * NKV + kv) * TT * HD; }
    #pragma unroll
    for (int m = 0; m < 4; ++m) {
      #pragma unroll
      for (int j = 0; j < 4; ++j) {
        const int t = wmw * 64 + m * 16 + rowg * 4 + j;
        float ss = 0.f;
        #pragma unroll
        for (int nn = 0; nn < 4; ++nn) { float v = acc[m][nn][j]; ss += v * v; }
        #pragma unroll
        for (int dlt = 1; dlt < 16; dlt <<= 1) ss += __shfl_xor(ss, dlt);
        const float r = rsqrtf(ss * (1.f / 64.f) + 1e-6f) * rs;
        #pragma unroll
        for (int nn = 0; nn < 4; ++nn)
          dst[(size_t)t * HD + nn * 16 + cl] = f2bf(acc[m][nn][j] * r * wfrag[nn]);
      }
    }
  }
}

// ---------------- kernel 2: attention per (n, kv-head), 3 q-heads ----------------
// Pl is wave-private (write rows wave*32+m*16+rowg*4+j; read rows
// wave*32+m*16+cl -> same 32-row band), so NO barriers inside the head loop:
// 8 free-running waves/CU hide each other's softmax chains. Soft cap via
// Pade tanh (|s/50| << 1 here); softmax without max-subtract (capped <= 50,
// exp(s-50), min realistic term ~1e-37, no flush).
__global__ __launch_bounds__(256)
void attn_kernel(const unsigned short* __restrict__ qb, const unsigned short* __restrict__ kb,
                 const unsigned short* __restrict__ vTb, unsigned short* __restrict__ ab) {
  extern __shared__ char smem[];
  unsigned short (*Ks)[72]   = reinterpret_cast<unsigned short (*)[72]>(smem);            // 18432
  unsigned short (*Vts)[136] = reinterpret_cast<unsigned short (*)[136]>(smem + 18432);   // 17408
  unsigned short (*Pl)[136]  = reinterpret_cast<unsigned short (*)[136]>(smem + 35840);   // 34816
  const int b = blockIdx.x;
  const int x8 = b & 7, idx = b >> 3;
  const int kv = idx & 3;
  const int n  = (idx >> 2) * 8 + x8;
  const int tid = threadIdx.x, wave = tid >> 6, lane = tid & 63;
  const int cl = lane & 15, rowg = lane >> 4;

  const unsigned short* ksrc = kb + (size_t)(n * NKV + kv) * TT * HD;
  const unsigned short* vsrc = vTb + (size_t)(n * NKV + kv) * HD * TT;
  #pragma unroll
  for (int i = 0; i < 4; ++i) {
    int c = tid + 256 * i, r = c >> 3, seg = c & 7;
    *reinterpret_cast<u32x4*>(&Ks[r][seg * 8]) = *reinterpret_cast<const u32x4*>(ksrc + c * 8);
  }
  #pragma unroll
  for (int i = 0; i < 4; ++i) {
    int c = tid + 256 * i, r = c >> 4, seg = c & 15;
    *reinterpret_cast<u32x4*>(&Vts[r][seg * 8]) = *reinterpret_cast<const u32x4*>(vsrc + c * 8);
  }
  __syncthreads();   // the only barrier

  for (int hh = 0; hh < 3; ++hh) {
    const int h = kv * 3 + hh;
    const unsigned short* qsrc = qb + (size_t)(n * NH + h) * TT * HD;
    f32x4 sc[2][8] = {};
    #pragma unroll
    for (int ks = 0; ks < 2; ++ks) {
      bf16x8 a[2], bbf[8];
      #pragma unroll
      for (int m = 0; m < 2; ++m)   // Q frags straight from global (L2-hot)
        a[m] = *reinterpret_cast<const bf16x8*>(
            qsrc + (size_t)(wave * 32 + m * 16 + cl) * HD + ks * 32 + rowg * 8);
      #pragma unroll
      for (int nn = 0; nn < 8; ++nn)
        bbf[nn] = *reinterpret_cast<const bf16x8*>(&Ks[nn * 16 + cl][ks * 32 + rowg * 8]);
      #pragma unroll
      for (int m = 0; m < 2; ++m)
        #pragma unroll
        for (int nn = 0; nn < 8; ++nn)
          sc[m][nn] = __builtin_amdgcn_mfma_f32_16x16x32_bf16(a[m], bbf[nn], sc[m][nn], 0, 0, 0);
    }
    // soft cap (Pade) + causal + no-max softmax; rows live in 16-lane groups
    #pragma unroll
    for (int m = 0; m < 2; ++m) {
      #pragma unroll
      for (int j = 0; j < 4; ++j) {
        const int rowv = wave * 32 + m * 16 + rowg * 4 + j;
        float e8[8];
        float sum = 0.f;
        #pragma unroll
        for (int nn = 0; nn < 8; ++nn) {
          float s = sc[m][nn][j];
          const float z2 = s * s * 4.0e-4f;
          s = s * (27.f + z2) * __builtin_amdgcn_rcpf(27.f + 9.f * z2);
          float e = __expf(s - 50.f);
          if (nn * 16 + cl > rowv) e = 0.f;
          e8[nn] = e;
          sum += e;
        }
        #pragma unroll
        for (int d = 1; d < 16; d <<= 1) sum += __shfl_xor(sum, d);
        const float inv = __builtin_amdgcn_rcpf(sum);
        #pragma unroll
        for (int nn = 0; nn < 8; ++nn)
          Pl[rowv][nn * 16 + cl] = f2bf(e8[nn] * inv);
      }
    }
    // PV: Pl rows are wave-private -> same-wave lgkmcnt dep, no barrier
    f32x4 o[2][4] = {};
    #pragma unroll
    for (int ks = 0; ks < 4; ++ks) {
      bf16x8 a[2], bbf[4];
      #pragma unroll
      for (int m = 0; m < 2; ++m)
        a[m] = *reinterpret_cast<const bf16x8*>(&Pl[wave * 32 + m * 16 + cl][ks * 32 + rowg * 8]);
      #pragma unroll
      for (int nn = 0; nn < 4; ++nn)
        bbf[nn] = *reinterpret_cast<const bf16x8*>(&Vts[nn * 16 + cl][ks * 32 + rowg * 8]);
      #pragma unroll
      for (int m = 0; m < 2; ++m)
        #pragma unroll
        for (int nn = 0; nn < 4; ++nn)
          o[m][nn] = __builtin_amdgcn_mfma_f32_16x16x32_bf16(a[m], bbf[nn], o[m][nn], 0, 0, 0);
    }
    unsigned short* dst = ab + (size_t)n * TT * DIM + h * HD;
    #pragma unroll
    for (int m = 0; m < 2; ++m)
      #pragma unroll
      for (int j = 0; j < 4; ++j) {
        int t = wave * 32 + m * 16 + rowg * 4 + j;
        #pragma unroll
        for (int nn = 0; nn < 4; ++nn)
          dst[(size_t)t * DIM + nn * 16 + cl] = f2bf(o[m][nn][j]);
      }
    // no barrier: next head rewrites only this wave's Pl rows
  }
}

// ---------------- kernel 3: output projection (R4 structure) ----------------
__global__ __launch_bounds__(512, 2)
void out_kernel(const unsigned short* __restrict__ ab, const unsigned short* __restrict__ WoT,
                float* __restrict__ out) {
  extern __shared__ unsigned short lds[];
  const int b = blockIdx.x;
  const int x8 = b & 7, idx = b >> 3;
  const int cbt = idx % 3;
  const int n   = (idx / 3) * 8 + x8;
  const int tid = threadIdx.x;
  const int wave = tid >> 6, lane = tid & 63;
  const int cl = lane & 15, rowg = lane >> 4;
  const int wmw = wave >> 2, wn = wave & 3;
  const int l8 = lane >> 3, s8 = lane & 7;
  const unsigned short* asrc = ab  + (size_t)(n * TT + l8) * DIM + (s8 ^ l8) * 8;
  const unsigned short* bsrc = WoT + (size_t)(cbt * 256 + l8) * DIM + (s8 ^ l8) * 8;
  const int swzr = (cl & 7) << 4;
  f32x4 acc[4][4] = {};

#define OUT_STAGE(buf, ko)                                                  \
  {                                                                         \
    unsigned short* Ad = lds + (buf) * 24576;                               \
    unsigned short* Bd = Ad + 8192;                                         \
    _Pragma("unroll")                                                       \
    for (int i = 0; i < 2; ++i) {                                           \
      const int rr = i * 64 + wave * 8;                                     \
      gload_lds16(asrc + (size_t)rr * DIM + (ko), Ad + rr * 64);            \
    }                                                                       \
    _Pragma("unroll")                                                       \
    for (int i = 0; i < 4; ++i) {                                           \
      const int rr = i * 64 + wave * 8;                                     \
      gload_lds16(bsrc + (size_t)rr * DIM + (ko), Bd + rr * 64);            \
    }                                                                       \
  }

  OUT_STAGE(0, 0);
  __syncthreads();
  for (int kt = 0; kt < 12; ++kt) {
    if (kt < 11) OUT_STAGE((kt + 1) & 1, (kt + 1) * 64);
    const char* Ab = (const char*)(lds + (kt & 1) * 24576);
    const char* Bb = Ab + 16384;
    #pragma unroll
    for (int ks = 0; ks < 2; ++ks) {
      bf16x8 a[4], bb[4];
      #pragma unroll
      for (int m = 0; m < 4; ++m)
        a[m] = *(const bf16x8*)(Ab + (wmw * 64 + m * 16 + cl) * 128 + ((ks * 64 + rowg * 16) ^ swzr));
      #pragma unroll
      for (int nn = 0; nn < 4; ++nn)
        bb[nn] = *(const bf16x8*)(Bb + (wn * 64 + nn * 16 + cl) * 128 + ((ks * 64 + rowg * 16) ^ swzr));
      #pragma unroll
      for (int m = 0; m < 4; ++m)
        #pragma unroll
        for (int nn = 0; nn < 4; ++nn)
          acc[m][nn] = __builtin_amdgcn_mfma_f32_16x16x32_bf16(a[m], bb[nn], acc[m][nn], 0, 0, 0);
    }
    __syncthreads();
  }
#undef OUT_STAGE
  #pragma unroll
  for (int m = 0; m < 4; ++m)
    #pragma unroll
    for (int j = 0; j < 4; ++j) {
      int t = wmw * 64 + m * 16 + rowg * 4 + j;
      #pragma unroll
      for (int nn = 0; nn < 4; ++nn)
        out[(size_t)(t * NS + n) * DIM + cbt * 256 + wn * 64 + nn * 16 + cl] = acc[m][nn][j];
    }
}

// ---------------- launch ----------------
extern "C" void kernel_launch(void* const* d_in, const int* in_sizes, int n_in,
                              void* d_out, int out_size, void* d_ws, size_t ws_size,
                              hipStream_t stream) {
  const float* x   = (const float*)d_in[0];
  const float* Wq  = (const float*)d_in[1];
  const float* Wk  = (const float*)d_in[2];
  const float* Wv  = (const float*)d_in[3];
  const float* Wo  = (const float*)d_in[4];
  const float* qnw = (const float*)d_in[5];
  const float* knw = (const float*)d_in[6];
  (void)in_sizes; (void)n_in; (void)out_size;

  char* ws = (char*)d_ws;
  unsigned short* Wt  = (unsigned short*)(ws + 0);          // 1,966,080
  unsigned short* WoT = (unsigned short*)(ws + 1966080);    // 1,179,648
  unsigned short* qb  = (unsigned short*)(ws + 3145728);    // 50,331,648
  unsigned short* kb  = (unsigned short*)(ws + 53477376);   // 16,777,216
  unsigned short* vTb = (unsigned short*)(ws + 70254592);   // 16,777,216
  unsigned short* ab  = (unsigned short*)(ws + 87031808);   // 50,331,648
  unsigned short* xb  = ab;                                 // alias (qkv reads xb before attn writes ab)
  if (ws_size < 137363456) return;

  hipFuncSetAttribute(reinterpret_cast<const void*>(qkv_kernel),
                      hipFuncAttributeMaxDynamicSharedMemorySize, 98304);
  hipFuncSetAttribute(reinterpret_cast<const void*>(out_kernel),
                      hipFuncAttributeMaxDynamicSharedMemorySize, 98304);
  hipFuncSetAttribute(reinterpret_cast<const void*>(attn_kernel),
                      hipFuncAttributeMaxDynamicSharedMemorySize, 70656);

  prep_kernel<<<30720, 256, 0, stream>>>(x, Wq, Wk, Wv, Wo, Wt, WoT, xb);
  qkv_kernel<<<1280, 512, 98304, stream>>>(xb, qnw, knw, Wt, qb, kb, vTb);
  attn_kernel<<<1024, 256, 70656, stream>>>(qb, kb, vTb, ab);
  out_kernel<<<768, 512, 98304, stream>>>(ab, WoT, (float*)d_out);
}